// Round 8
// baseline (169.872 us; speedup 1.0000x reference)
//
#include <hip/hip_runtime.h>
#include <math.h>
#include <stdint.h>

#ifndef TAU_CONST
#define TAU_CONST 1.0f
#endif

typedef float v4f __attribute__((ext_vector_type(4)));

// ---------------- math (unchanged) ----------------

__device__ __forceinline__ void rbox_to_gauss(float x, float y, float w, float h, float r,
                                              float& mx, float& my,
                                              float& s00, float& s01, float& s11, float& det) {
    w = fminf(fmaxf(w, 1e-7f), 1e7f);
    h = fminf(fmaxf(h, 1e-7f), 1e7f);
    float a = 0.25f * w * w;   // (w/2)^2
    float b = 0.25f * h * h;   // (h/2)^2
    float s2, c2;
    __sincosf(r + r, &s2, &c2);          // sin 2r, cos 2r
    float hs = 0.5f * (a + b);
    float hd = 0.5f * (a - b);
    s00 = fmaf(hd, c2, hs);
    s11 = fmaf(-hd, c2, hs);
    s01 = hd * s2;
    det = a * b;                          // det(R S R^T) == a*b exactly
    mx = x; my = y;
}

__device__ __forceinline__ float kld_row(const float* p, const float* t) {
    float pmx, pmy, p00, p01, p11, dp;
    float tmx, tmy, t00, t01, t11, dt;
    rbox_to_gauss(p[0], p[1], p[2], p[3], p[4], pmx, pmy, p00, p01, p11, dp);
    rbox_to_gauss(t[0], t[1], t[2], t[3], t[4], tmx, tmy, t00, t01, t11, dt);
    float dx = pmx - tmx, dy = pmy - tmy;
    float inv_dt = __builtin_amdgcn_rcpf(dt);
    float inv_dp = __builtin_amdgcn_rcpf(dp);
    float term1 = (dx * dx * t11 - 2.0f * dx * dy * t01 + dy * dy * t00) * inv_dt;
    float tr = (t11 * p00 + t00 * p11 - 2.0f * t01 * p01) * inv_dt;
    float term2 = tr + __logf(dt * inv_dp);
    float dis = term1 + term2 - 2.0f;
    float kl = fmaxf(dis, 1e-6f);
    float l1p = __logf(1.0f + kl);
    return 1.0f - __builtin_amdgcn_rcpf(TAU_CONST + l1p);
}

// ---------- persistent pipeline, REGISTER-staged (TCP path), NT policy ----------
// Round-7 retry with FIXED tile arithmetic:
//   TILE_ROWS=1024 -> 5120 floats = 1280 v4f per input = exactly 5 v4f x 256 thr.
// Streaming via NT register loads (global_load_dwordx4 nt) + ds_write_b128 --
// NOT the LDS-DMA engine. In-flight bytes live in VGPRs: 40 KB/block x
// 4 blocks/CU = 160 KB/CU outstanding (T14: issue-early / write-late).
// LDS = 40 KB single-buffered transpose scratch, two barriers per tile.

#define TILE_ROWS 1024
#define TILE_FLOATS (TILE_ROWS * 5)   // 5120 floats = 20 KB per input per tile

__global__ void __launch_bounds__(256, 4)
gdloss_regpipe_kernel(const float* __restrict__ pred,
                      const float* __restrict__ target,
                      float* __restrict__ out, int ntiles) {
    __shared__ float lds[2 * TILE_FLOATS];   // [pred 5120 | tgt 5120] floats, 40 KB
    const int tid = threadIdx.x;
    const int stride = gridDim.x;

    v4f pv[5], tv[5];
    int t = blockIdx.x;
    // prologue: issue tile-t loads into registers (coalesced, NT)
    if (t < ntiles) {
        const v4f* pb = (const v4f*)(pred   + (long long)t * TILE_FLOATS);
        const v4f* tb = (const v4f*)(target + (long long)t * TILE_FLOATS);
#pragma unroll
        for (int k = 0; k < 5; ++k) {
            pv[k] = __builtin_nontemporal_load(pb + k * 256 + tid);
            tv[k] = __builtin_nontemporal_load(tb + k * 256 + tid);
        }
    }

    for (; t < ntiles; t += stride) {
        __syncthreads();   // everyone done READING lds for the previous tile
        // write-late: staged regs -> LDS (waits the loads' vmcnt as needed)
#pragma unroll
        for (int k = 0; k < 5; ++k) {
            ((v4f*)lds)[k * 256 + tid] = pv[k];                      // 1280 v4f pred
            ((v4f*)(lds + TILE_FLOATS))[k * 256 + tid] = tv[k];      // 1280 v4f tgt
        }
        __syncthreads();   // tile t fully visible in LDS

        // issue-early: next tile's loads into the now-free staging regs.
        int tn = t + stride;
        if (tn < ntiles) {
            const v4f* pb = (const v4f*)(pred   + (long long)tn * TILE_FLOATS);
            const v4f* tb = (const v4f*)(target + (long long)tn * TILE_FLOATS);
#pragma unroll
            for (int k = 0; k < 5; ++k) {
                pv[k] = __builtin_nontemporal_load(pb + k * 256 + tid);
                tv[k] = __builtin_nontemporal_load(tb + k * 256 + tid);
            }
        }

        // compute: 4 rows/thread, 20 consecutive floats at float index 20*tid
        // (80 B, 16-B aligned -> 5 x ds_read_b128; bank starts 20*tid mod 32
        // cover all 32 banks per 8 lanes -> conflict-free)
        const v4f* lp = (const v4f*)&lds[20 * tid];
        const v4f* lt = (const v4f*)&lds[TILE_FLOATS + 20 * tid];
        float pf[20], tf[20];
#pragma unroll
        for (int k = 0; k < 5; ++k) {
            v4f a = lp[k], b = lt[k];
            pf[4 * k + 0] = a.x; pf[4 * k + 1] = a.y; pf[4 * k + 2] = a.z; pf[4 * k + 3] = a.w;
            tf[4 * k + 0] = b.x; tf[4 * k + 1] = b.y; tf[4 * k + 2] = b.z; tf[4 * k + 3] = b.w;
        }
        v4f o;
        o.x = kld_row(pf + 0,  tf + 0);
        o.y = kld_row(pf + 5,  tf + 5);
        o.z = kld_row(pf + 10, tf + 10);
        o.w = kld_row(pf + 15, tf + 15);
        __builtin_nontemporal_store(o, (v4f*)out + (long long)t * 256 + tid);
    }
}

// Scalar tail (rows not covered by full 1024-row tiles).
__global__ void gdloss_tail_kernel(const float* __restrict__ pred,
                                   const float* __restrict__ target,
                                   float* __restrict__ out, int start, int n) {
    int i = start + blockIdx.x * blockDim.x + threadIdx.x;
    if (i >= n) return;
    float p[5], t[5];
#pragma unroll
    for (int k = 0; k < 5; ++k) {
        p[k] = pred[5 * i + k];
        t[k] = target[5 * i + k];
    }
    out[i] = kld_row(p, t);
}

extern "C" void kernel_launch(void* const* d_in, const int* in_sizes, int n_in,
                              void* d_out, int out_size, void* d_ws, size_t ws_size,
                              hipStream_t stream) {
    const float* pred   = (const float*)d_in[0];
    const float* target = (const float*)d_in[1];
    float* out = (float*)d_out;
    int n      = in_sizes[0] / 5;          // rows
    int ntiles = n / TILE_ROWS;
    if (ntiles > 0) {
        int blocks = ntiles < 1024 ? ntiles : 1024;   // 4 blocks/CU, persistent
        gdloss_regpipe_kernel<<<blocks, 256, 0, stream>>>(pred, target, out, ntiles);
    }
    int start = ntiles * TILE_ROWS;
    int rem = n - start;
    if (rem > 0) {
        int tb = (rem + 255) / 256;
        gdloss_tail_kernel<<<tb, 256, 0, stream>>>(pred, target, out, start, n);
    }
}

// Round 9
// 165.348 us; speedup vs baseline: 1.0274x; 1.0274x over previous
//
#include <hip/hip_runtime.h>
#include <math.h>
#include <stdint.h>

#ifndef TAU_CONST
#define TAU_CONST 1.0f
#endif

typedef float v4f __attribute__((ext_vector_type(4)));

// ---------------- math (unchanged) ----------------

__device__ __forceinline__ void rbox_to_gauss(float x, float y, float w, float h, float r,
                                              float& mx, float& my,
                                              float& s00, float& s01, float& s11, float& det) {
    w = fminf(fmaxf(w, 1e-7f), 1e7f);
    h = fminf(fmaxf(h, 1e-7f), 1e7f);
    float a = 0.25f * w * w;   // (w/2)^2
    float b = 0.25f * h * h;   // (h/2)^2
    float s2, c2;
    __sincosf(r + r, &s2, &c2);          // sin 2r, cos 2r
    float hs = 0.5f * (a + b);
    float hd = 0.5f * (a - b);
    s00 = fmaf(hd, c2, hs);
    s11 = fmaf(-hd, c2, hs);
    s01 = hd * s2;
    det = a * b;                          // det(R S R^T) == a*b exactly
    mx = x; my = y;
}

__device__ __forceinline__ float kld_row(const float* p, const float* t) {
    float pmx, pmy, p00, p01, p11, dp;
    float tmx, tmy, t00, t01, t11, dt;
    rbox_to_gauss(p[0], p[1], p[2], p[3], p[4], pmx, pmy, p00, p01, p11, dp);
    rbox_to_gauss(t[0], t[1], t[2], t[3], t[4], tmx, tmy, t00, t01, t11, dt);
    float dx = pmx - tmx, dy = pmy - tmy;
    float inv_dt = __builtin_amdgcn_rcpf(dt);
    float inv_dp = __builtin_amdgcn_rcpf(dp);
    float term1 = (dx * dx * t11 - 2.0f * dx * dy * t01 + dy * dy * t00) * inv_dt;
    float tr = (t11 * p00 + t00 * p11 - 2.0f * t01 * p01) * inv_dt;
    float term2 = tr + __logf(dt * inv_dp);
    float dis = term1 + term2 - 2.0f;
    float kl = fmaxf(dis, 1e-6f);
    float l1p = __logf(1.0f + kl);
    return 1.0f - __builtin_amdgcn_rcpf(TAU_CONST + l1p);
}

// ------------- DUAL-PATH persistent pipeline (A/B vs round 6's 52 us) -------------
// Identical persistent double-buffered structure; the ONLY change: chunk transport
// is split across the two independent hardware paths per CU:
//   waves 0,2 -> LDS-DMA engine (global_load_lds, aux=2 NT)
//   waves 1,3 -> TCP vector loads (NT reg-load, write-late ds_write_b128)
// If each path has its own ~3.3 TB/s queue limit, read streams sum -> ~2x.
// If the fabric read-cap is global, this is null -> roofline evidence complete.

__device__ __forceinline__ void gload_lds16_nt(const void* g, void* l) {
    __builtin_amdgcn_global_load_lds((const __attribute__((address_space(1))) uint32_t*)g,
                                     (__attribute__((address_space(3))) uint32_t*)l,
                                     16, 0, /*aux: NT*/ 2);
}

#define ROWS_PER_TILE 256
#define FLOATS_PER_TILE (ROWS_PER_TILE * 5)   // 1280 floats per input per tile

__global__ void __launch_bounds__(256, 8)
gdloss_dual_kernel(const float* __restrict__ pred,
                   const float* __restrict__ target,
                   float* __restrict__ out, int ntiles) {
    __shared__ float lds[2][2 * FLOATS_PER_TILE];  // [buf][pred 1280 | tgt 1280]
    const int tid = threadIdx.x;
    const int wv  = tid >> 6;
    const int ln  = tid & 63;
    const int stride = gridDim.x;
    const bool reg_wave = (wv & 1);               // waves 1,3: TCP path

    v4f rv[3];                                    // reg-wave staging (<=3 chunks)

    // chunk c (0..9): source pointer for tile tt, lane ln
    auto chunk_src = [&](int tt, int c) -> const float* {
        return (c < 5) ? (pred   + (long long)tt * FLOATS_PER_TILE + c * 256 + ln * 4)
                       : (target + (long long)tt * FLOATS_PER_TILE + (c - 5) * 256 + ln * 4);
    };

    int t = blockIdx.x;
    // prologue: stage tile t into buf 0 (reg waves: load+write serially, once)
    if (t < ntiles) {
#pragma unroll
        for (int j = 0; j < 3; ++j) {
            int c = wv + 4 * j;
            if (c < 10) {
                if (reg_wave) {
                    rv[j] = __builtin_nontemporal_load((const v4f*)chunk_src(t, c));
                } else {
                    gload_lds16_nt(chunk_src(t, c), &lds[0][c * 256]);
                }
            }
        }
        if (reg_wave) {
#pragma unroll
            for (int j = 0; j < 3; ++j) {
                int c = wv + 4 * j;
                if (c < 10) ((v4f*)&lds[0][c * 256])[ln] = rv[j];
            }
        }
    }

    int buf = 0;
    for (; t < ntiles; t += stride) {
        __syncthreads();                 // tile t resident in lds[buf]
        int tn = t + stride;
        if (tn < ntiles) {               // issue next tile into buf^1
#pragma unroll
            for (int j = 0; j < 3; ++j) {
                int c = wv + 4 * j;
                if (c < 10) {
                    if (reg_wave) {
                        rv[j] = __builtin_nontemporal_load((const v4f*)chunk_src(tn, c));
                    } else {
                        gload_lds16_nt(chunk_src(tn, c), &lds[buf ^ 1][c * 256]);
                    }
                }
            }
        }
        // compute tile t: one row/thread, 5 consecutive floats at 5*tid
        // (gcd(5,32)=1 -> 2 lanes/bank = conflict-free; measured 0 conflicts)
        const float* lp = &lds[buf][5 * tid];
        const float* lt = &lds[buf][FLOATS_PER_TILE + 5 * tid];
        float p[5], tt[5];
#pragma unroll
        for (int k = 0; k < 5; ++k) { p[k] = lp[k]; tt[k] = lt[k]; }
        float r = kld_row(p, tt);
        __builtin_nontemporal_store(r, &out[(long long)t * ROWS_PER_TILE + tid]);

        // write-late: reg-wave staged chunks -> lds[buf^1] (loads flew during compute)
        if (tn < ntiles && reg_wave) {
#pragma unroll
            for (int j = 0; j < 3; ++j) {
                int c = wv + 4 * j;
                if (c < 10) ((v4f*)&lds[buf ^ 1][c * 256])[ln] = rv[j];
            }
        }
        buf ^= 1;
    }
}

// Scalar tail (rows not covered by full tiles; none at N=4M).
__global__ void gdloss_tail_kernel(const float* __restrict__ pred,
                                   const float* __restrict__ target,
                                   float* __restrict__ out, int start, int n) {
    int i = start + blockIdx.x * blockDim.x + threadIdx.x;
    if (i >= n) return;
    float p[5], t[5];
#pragma unroll
    for (int k = 0; k < 5; ++k) {
        p[k] = pred[5 * i + k];
        t[k] = target[5 * i + k];
    }
    out[i] = kld_row(p, t);
}

extern "C" void kernel_launch(void* const* d_in, const int* in_sizes, int n_in,
                              void* d_out, int out_size, void* d_ws, size_t ws_size,
                              hipStream_t stream) {
    const float* pred   = (const float*)d_in[0];
    const float* target = (const float*)d_in[1];
    float* out = (float*)d_out;
    int n      = in_sizes[0] / 5;          // rows
    int ntiles = n / ROWS_PER_TILE;
    if (ntiles > 0) {
        int blocks = ntiles < 2048 ? ntiles : 2048;   // 8 blocks/CU, persistent
        gdloss_dual_kernel<<<blocks, 256, 0, stream>>>(pred, target, out, ntiles);
    }
    int start = ntiles * ROWS_PER_TILE;
    int rem = n - start;
    if (rem > 0) {
        int tb = (rem + 255) / 256;
        gdloss_tail_kernel<<<tb, 256, 0, stream>>>(pred, target, out, start, n);
    }
}